// Round 1
// baseline (761.861 us; speedup 1.0000x reference)
//
#include <hip/hip_runtime.h>

#define B_ 4
#define T_ 4096
#define E_ 512
#define A_ 64

// ---------------- Kernel 1: QKV projection ----------------
// emb [B*T, E] fp32, W* [E, A] fp32 -> Q (pre-scaled by 1/8), K, V [B*T, A] fp32
// 512 blocks x 256 threads; each block handles 32 rows. Weights stream from L2.
__global__ __launch_bounds__(256) void qkv_proj_kernel(
    const float* __restrict__ emb, const float* __restrict__ Wq,
    const float* __restrict__ Wk, const float* __restrict__ Wv,
    float* __restrict__ Q, float* __restrict__ K, float* __restrict__ V)
{
    __shared__ float etile[32 * 512];   // 64 KB
    const int tid = threadIdx.x;
    const long rowbase = (long)blockIdx.x * 32;
    {
        const float4* src = (const float4*)(emb + rowbase * 512);
        float4* dst = (float4*)etile;
        #pragma unroll
        for (int it = 0; it < 16; ++it)
            dst[it * 256 + tid] = src[it * 256 + tid];
    }
    __syncthreads();
    const int lane = tid & 63;   // output dim a
    const int w = tid >> 6;      // wave: rows w*8 .. w*8+7
    float accq[8], acck[8], accv[8];
    #pragma unroll
    for (int q = 0; q < 8; ++q) { accq[q] = 0.f; acck[q] = 0.f; accv[q] = 0.f; }

    for (int e4 = 0; e4 < 128; ++e4) {
        float wqv[4], wkv[4], wvv[4];
        #pragma unroll
        for (int u = 0; u < 4; ++u) {
            const int e = e4 * 4 + u;
            wqv[u] = Wq[e * 64 + lane];
            wkv[u] = Wk[e * 64 + lane];
            wvv[u] = Wv[e * 64 + lane];
        }
        #pragma unroll
        for (int q = 0; q < 8; ++q) {
            const float4 x = *(const float4*)&etile[(w * 8 + q) * 512 + e4 * 4];
            accq[q] = fmaf(x.x, wqv[0], fmaf(x.y, wqv[1], fmaf(x.z, wqv[2], fmaf(x.w, wqv[3], accq[q]))));
            acck[q] = fmaf(x.x, wkv[0], fmaf(x.y, wkv[1], fmaf(x.z, wkv[2], fmaf(x.w, wkv[3], acck[q]))));
            accv[q] = fmaf(x.x, wvv[0], fmaf(x.y, wvv[1], fmaf(x.z, wvv[2], fmaf(x.w, wvv[3], accv[q]))));
        }
    }
    #pragma unroll
    for (int q = 0; q < 8; ++q) {
        const long r = rowbase + w * 8 + q;
        Q[r * 64 + lane] = accq[q] * 0.125f;   // fold 1/sqrt(64) into Q
        K[r * 64 + lane] = acck[q];
        V[r * 64 + lane] = accv[q];
    }
}

// ---------------- Kernel 2: causal flash attention (fp32) ----------------
// Block = 256 threads (4 waves). Each block processes q-tiles {pt, 127-pt} of 32
// rows each (causal load balancing: every block does ~65 key-chunks of 64).
// Wave w owns 8 q-rows. Lane = key index in QK phase, = output dim in PV phase.
__global__ __launch_bounds__(256) void attn_kernel(
    const float* __restrict__ Q, const float* __restrict__ K,
    const float* __restrict__ V, float* __restrict__ out)
{
    __shared__ float q_lds[32 * 64];     // 8 KB, plain row-major (broadcast reads)
    __shared__ float k_lds[64 * 64];     // 16 KB, float4-col xor-swizzled rows
    __shared__ float vt_lds[64 * 68];    // 17.4 KB, transposed V, row stride 68
    __shared__ float p_lds[32 * 68];     // 8.7 KB, row stride 68 (16B-aligned rows)

    const int tid = threadIdx.x;
    const int lane = tid & 63;
    const int w = tid >> 6;
    const int c4 = tid & 15;     // float4 column for staging
    const int r0 = tid >> 4;     // row group for staging
    const int b = blockIdx.x >> 6;
    const int pt = blockIdx.x & 63;
    const long boff = (long)b * T_ * A_;

    for (int ti = 0; ti < 2; ++ti) {
        const int tile = ti ? (127 - pt) : pt;
        const int qb = tile * 32;

        __syncthreads();   // protect q_lds reuse across tile iterations
        #pragma unroll
        for (int it = 0; it < 2; ++it) {
            const int lin = it * 256 + tid;       // float4 index in 32x16
            const int row = lin >> 4, cc = lin & 15;
            *(float4*)&q_lds[row * 64 + cc * 4] =
                *(const float4*)&Q[boff + (long)(qb + row) * 64 + cc * 4];
        }

        float m_s[8], l_s[8], acc[8];
        #pragma unroll
        for (int q = 0; q < 8; ++q) { m_s[q] = -1e30f; l_s[q] = 0.f; acc[q] = 0.f; }

        const int s_end = qb + 31;   // last valid key for this tile
        for (int s0 = 0; s0 <= s_end; s0 += 64) {
            __syncthreads();   // previous chunk's compute done before restage
            #pragma unroll
            for (int it = 0; it < 4; ++it) {
                const int r = r0 + it * 16;
                const float4 kv = *(const float4*)&K[boff + (long)(s0 + r) * 64 + c4 * 4];
                *(float4*)&k_lds[r * 64 + ((c4 ^ (r & 7)) << 2)] = kv;
                const float4 vv = *(const float4*)&V[boff + (long)(s0 + r) * 64 + c4 * 4];
                vt_lds[(c4 * 4 + 0) * 68 + r] = vv.x;
                vt_lds[(c4 * 4 + 1) * 68 + r] = vv.y;
                vt_lds[(c4 * 4 + 2) * 68 + r] = vv.z;
                vt_lds[(c4 * 4 + 3) * 68 + r] = vv.w;
            }
            __syncthreads();

            // ---- QK^T: lane = key k, 8 q-rows per thread ----
            float s[8];
            #pragma unroll
            for (int q = 0; q < 8; ++q) s[q] = 0.f;
            #pragma unroll
            for (int dq = 0; dq < 16; ++dq) {
                const float4 kv = *(const float4*)&k_lds[lane * 64 + ((dq ^ (lane & 7)) << 2)];
                #pragma unroll
                for (int q = 0; q < 8; ++q) {
                    const float4 qv = *(const float4*)&q_lds[(w * 8 + q) * 64 + dq * 4];
                    s[q] = fmaf(qv.x, kv.x, fmaf(qv.y, kv.y, fmaf(qv.z, kv.z, fmaf(qv.w, kv.w, s[q]))));
                }
            }

            // ---- online softmax (per q-row, across 64 lanes) ----
            const int qa0 = qb + w * 8;
            #pragma unroll
            for (int q = 0; q < 8; ++q) {
                const int qa = qa0 + q;
                const float sv = (s0 + lane <= qa) ? s[q] : -1e30f;
                float cm = sv;
                #pragma unroll
                for (int d = 1; d < 64; d <<= 1) cm = fmaxf(cm, __shfl_xor(cm, d));
                const float mnew = fmaxf(m_s[q], cm);
                const float scale = __expf(m_s[q] - mnew);
                const float p = __expf(sv - mnew);
                float cs = p;
                #pragma unroll
                for (int d = 1; d < 64; d <<= 1) cs += __shfl_xor(cs, d);
                l_s[q] = l_s[q] * scale + cs;
                acc[q] *= scale;
                m_s[q] = mnew;
                p_lds[(w * 8 + q) * 68 + lane] = p;
            }
            __syncthreads();   // conservative: ensure P visible before PV reads

            // ---- PV: lane = output dim d ----
            #pragma unroll
            for (int j4 = 0; j4 < 16; ++j4) {
                const float4 v4 = *(const float4*)&vt_lds[lane * 68 + j4 * 4];
                #pragma unroll
                for (int q = 0; q < 8; ++q) {
                    const float4 p4 = *(const float4*)&p_lds[(w * 8 + q) * 68 + j4 * 4];
                    acc[q] = fmaf(p4.x, v4.x, fmaf(p4.y, v4.y, fmaf(p4.z, v4.z, fmaf(p4.w, v4.w, acc[q]))));
                }
            }
        }

        #pragma unroll
        for (int q = 0; q < 8; ++q) {
            const long r = (long)b * T_ + qb + w * 8 + q;
            out[r * 64 + lane] = acc[q] / l_s[q];
        }
    }
}

extern "C" void kernel_launch(void* const* d_in, const int* in_sizes, int n_in,
                              void* d_out, int out_size, void* d_ws, size_t ws_size,
                              hipStream_t stream)
{
    const float* emb = (const float*)d_in[0];
    const float* Wq  = (const float*)d_in[1];
    const float* Wk  = (const float*)d_in[2];
    const float* Wv  = (const float*)d_in[3];
    float* out = (float*)d_out;

    float* Qs = (float*)d_ws;                       // 4 MB each, 12 MB total
    float* Ks = Qs + (size_t)B_ * T_ * A_;
    float* Vs = Ks + (size_t)B_ * T_ * A_;

    qkv_proj_kernel<<<dim3(512), dim3(256), 0, stream>>>(emb, Wq, Wk, Wv, Qs, Ks, Vs);
    attn_kernel<<<dim3(256), dim3(256), 0, stream>>>(Qs, Ks, Vs, out);
}

// Round 2
// 134.061 us; speedup vs baseline: 5.6830x; 5.6830x over previous
//
#include <hip/hip_runtime.h>

#define B_ 4
#define T_ 4096
#define E_ 512
#define A_ 64

typedef __attribute__((ext_vector_type(8))) short bf16x8;
typedef __attribute__((ext_vector_type(8))) unsigned short ushort8;
typedef __attribute__((ext_vector_type(4))) float f32x4;

__device__ __forceinline__ unsigned short f2bf(float x) {
    union { float f; unsigned int u; } v; v.f = x;
    unsigned int r = v.u + 0x7fffu + ((v.u >> 16) & 1u);
    return (unsigned short)(r >> 16);
}

// ---------------- Kernel 1: QKV projection (fp32 compute -> bf16 out) -------
// Outputs: Q bf16 [B*T][64] (pre-scaled 1/8), K bf16 [B*T][64], Vt bf16 [B][64][T].
__global__ __launch_bounds__(256) void qkv_proj_kernel(
    const float* __restrict__ emb, const float* __restrict__ Wq,
    const float* __restrict__ Wk, const float* __restrict__ Wv,
    unsigned short* __restrict__ Qo, unsigned short* __restrict__ Ko,
    unsigned short* __restrict__ Vto)
{
    __shared__ float etile[32 * 512];     // 64 KB
    __shared__ float vtile[32][65];       // 8.1 KB, padded for transpose reads
    const int tid = threadIdx.x;
    const long rowbase = (long)blockIdx.x * 32;
    {
        const float4* src = (const float4*)(emb + rowbase * 512);
        float4* dst = (float4*)etile;
        #pragma unroll
        for (int it = 0; it < 16; ++it)
            dst[it * 256 + tid] = src[it * 256 + tid];
    }
    __syncthreads();
    const int lane = tid & 63;   // output dim a
    const int w = tid >> 6;      // wave: rows w*8 .. w*8+7
    float accq[8], acck[8], accv[8];
    #pragma unroll
    for (int q = 0; q < 8; ++q) { accq[q] = 0.f; acck[q] = 0.f; accv[q] = 0.f; }

    for (int e4 = 0; e4 < 128; ++e4) {
        float wqv[4], wkv[4], wvv[4];
        #pragma unroll
        for (int u = 0; u < 4; ++u) {
            const int e = e4 * 4 + u;
            wqv[u] = Wq[e * 64 + lane];
            wkv[u] = Wk[e * 64 + lane];
            wvv[u] = Wv[e * 64 + lane];
        }
        #pragma unroll
        for (int q = 0; q < 8; ++q) {
            const float4 x = *(const float4*)&etile[(w * 8 + q) * 512 + e4 * 4];
            accq[q] = fmaf(x.x, wqv[0], fmaf(x.y, wqv[1], fmaf(x.z, wqv[2], fmaf(x.w, wqv[3], accq[q]))));
            acck[q] = fmaf(x.x, wkv[0], fmaf(x.y, wkv[1], fmaf(x.z, wkv[2], fmaf(x.w, wkv[3], acck[q]))));
            accv[q] = fmaf(x.x, wvv[0], fmaf(x.y, wvv[1], fmaf(x.z, wvv[2], fmaf(x.w, wvv[3], accv[q]))));
        }
    }
    #pragma unroll
    for (int q = 0; q < 8; ++q) {
        const long r = rowbase + w * 8 + q;
        Qo[r * 64 + lane] = f2bf(accq[q] * 0.125f);   // fold 1/sqrt(64)
        Ko[r * 64 + lane] = f2bf(acck[q]);
        vtile[w * 8 + q][lane] = accv[q];
    }
    __syncthreads();
    // transpose V tile: write Vt[b][d][t], 16B per thread
    const int d = tid >> 2, sg = tid & 3;
    ushort8 pk;
    #pragma unroll
    for (int j = 0; j < 8; ++j) pk[j] = f2bf(vtile[sg * 8 + j][d]);
    const int bb = (int)(rowbase >> 12);
    const int tloc = (int)(rowbase & 4095);
    *(ushort8*)&Vto[((long)bb * 64 + d) * T_ + tloc + sg * 8] = pk;
}

// ---------------- Kernel 2: causal flash attention (bf16 MFMA) --------------
// 1024 blocks = 4 batches x 256 tiles of 16 q-rows, largest tile first.
// Block = 4 waves; wave w handles key-chunks {w, w+4, ...} of 64 keys (split-K,
// online softmax per wave), merged at tile end via LDS. K/Vt B-frags read
// straight from global (L2/L3-resident, 4 MB total). Only P + merge in LDS.
__global__ __launch_bounds__(256, 4) void attn_kernel(
    const unsigned short* __restrict__ Q, const unsigned short* __restrict__ K,
    const unsigned short* __restrict__ Vt, float* __restrict__ out)
{
    __shared__ float p_lds[4][16][68];    // 17.0 KB
    __shared__ float accbuf[4][16][66];   // 16.5 KB
    __shared__ float mbuf[4][16];
    __shared__ float lbuf[4][16];

    const int tid = threadIdx.x;
    const int w = tid >> 6;
    const int lane = tid & 63;
    const int hi = lane >> 4;
    const int c = lane & 15;
    const int b = blockIdx.x & 3;
    const int t = 255 - (blockIdx.x >> 2);   // big tiles dispatched first
    const int qb = t << 4;

    const unsigned short* Qb = Q + ((long)b * T_ + qb) * 64;
    const unsigned short* Kb = K + (long)b * T_ * 64;
    const unsigned short* Vb = Vt + (long)b * 64 * T_;

    // Q A-frags held in registers for the whole tile
    const bf16x8 qf0 = *(const bf16x8*)&Qb[c * 64 + hi * 8];
    const bf16x8 qf1 = *(const bf16x8*)&Qb[c * 64 + 32 + hi * 8];

    float m[4], l[4];
    f32x4 acc[4];
    #pragma unroll
    for (int r = 0; r < 4; ++r) { m[r] = -1e30f; l[r] = 0.f; }
    #pragma unroll
    for (int dt = 0; dt < 4; ++dt) acc[dt] = (f32x4){0.f, 0.f, 0.f, 0.f};

    const int nc = ((qb + 15) >> 6) + 1;
    for (int ci = w; ci < nc; ci += 4) {
        const int s0 = ci << 6;
        // ---- S = Q K^T (16q x 64k), 8 MFMA ----
        f32x4 sf[4];
        #pragma unroll
        for (int f = 0; f < 4; ++f) sf[f] = (f32x4){0.f, 0.f, 0.f, 0.f};
        #pragma unroll
        for (int f = 0; f < 4; ++f) {
            const unsigned short* kp = &Kb[(long)(s0 + f * 16 + c) * 64 + hi * 8];
            const bf16x8 k0 = *(const bf16x8*)kp;
            const bf16x8 k1 = *(const bf16x8*)(kp + 32);
            sf[f] = __builtin_amdgcn_mfma_f32_16x16x32_bf16(qf0, k0, sf[f], 0, 0, 0);
            sf[f] = __builtin_amdgcn_mfma_f32_16x16x32_bf16(qf1, k1, sf[f], 0, 0, 0);
        }
        // ---- causal mask (only the diagonal-straddling chunk needs it) ----
        if (s0 + 63 > qb) {
            #pragma unroll
            for (int f = 0; f < 4; ++f)
                #pragma unroll
                for (int r = 0; r < 4; ++r)
                    if (s0 + f * 16 + c > qb + hi * 4 + r) sf[f][r] = -1e30f;
        }
        // ---- online softmax; D-frag: col=c is key, row=hi*4+r is q-row ----
        #pragma unroll
        for (int r = 0; r < 4; ++r) {
            float rm = fmaxf(fmaxf(sf[0][r], sf[1][r]), fmaxf(sf[2][r], sf[3][r]));
            rm = fmaxf(rm, __shfl_xor(rm, 1));
            rm = fmaxf(rm, __shfl_xor(rm, 2));
            rm = fmaxf(rm, __shfl_xor(rm, 4));
            rm = fmaxf(rm, __shfl_xor(rm, 8));
            const float mn = fmaxf(m[r], rm);
            const float sc = __expf(m[r] - mn);
            m[r] = mn;
            float rs = 0.f;
            #pragma unroll
            for (int f = 0; f < 4; ++f) {
                const float pv = (sf[f][r] > -1e29f) ? __expf(sf[f][r] - mn) : 0.f;
                p_lds[w][hi * 4 + r][f * 16 + c] = pv;
                rs += pv;
            }
            rs += __shfl_xor(rs, 1);
            rs += __shfl_xor(rs, 2);
            rs += __shfl_xor(rs, 4);
            rs += __shfl_xor(rs, 8);
            l[r] = l[r] * sc + rs;
            #pragma unroll
            for (int dt = 0; dt < 4; ++dt) acc[dt][r] *= sc;
        }
        asm volatile("s_waitcnt lgkmcnt(0)" ::: "memory");  // P write -> cross-lane read
        // ---- O += P V (16q x 64d), 8 MFMA; V frags from global Vt ----
        #pragma unroll
        for (int kk = 0; kk < 2; ++kk) {
            const f32x4 plo = *(const f32x4*)&p_lds[w][c][kk * 32 + hi * 8];
            const f32x4 phi = *(const f32x4*)&p_lds[w][c][kk * 32 + hi * 8 + 4];
            bf16x8 pa;
            #pragma unroll
            for (int j = 0; j < 4; ++j) {
                pa[j]     = (short)f2bf(plo[j]);
                pa[j + 4] = (short)f2bf(phi[j]);
            }
            #pragma unroll
            for (int dt = 0; dt < 4; ++dt) {
                const bf16x8 vf = *(const bf16x8*)&Vb[(long)(dt * 16 + c) * T_ + s0 + kk * 32 + hi * 8];
                acc[dt] = __builtin_amdgcn_mfma_f32_16x16x32_bf16(pa, vf, acc[dt], 0, 0, 0);
            }
        }
    }

    // ---- merge the 4 waves' split-K partial states ----
    if (c == 0) {
        #pragma unroll
        for (int r = 0; r < 4; ++r) { mbuf[w][hi * 4 + r] = m[r]; lbuf[w][hi * 4 + r] = l[r]; }
    }
    #pragma unroll
    for (int dt = 0; dt < 4; ++dt)
        #pragma unroll
        for (int r = 0; r < 4; ++r)
            accbuf[w][hi * 4 + r][dt * 16 + c] = acc[dt][r];
    __syncthreads();
    #pragma unroll
    for (int i = 0; i < 4; ++i) {
        const int e = tid + i * 256;
        const int q = e >> 6, d = e & 63;
        const float ms = fmaxf(fmaxf(mbuf[0][q], mbuf[1][q]), fmaxf(mbuf[2][q], mbuf[3][q]));
        float lsum = 0.f, osum = 0.f;
        #pragma unroll
        for (int wv = 0; wv < 4; ++wv) {
            const float e_ = __expf(mbuf[wv][q] - ms);
            lsum += lbuf[wv][q] * e_;
            osum += accbuf[wv][q][d] * e_;
        }
        out[((long)b * T_ + qb + q) * 64 + d] = osum / lsum;
    }
}

extern "C" void kernel_launch(void* const* d_in, const int* in_sizes, int n_in,
                              void* d_out, int out_size, void* d_ws, size_t ws_size,
                              hipStream_t stream)
{
    const float* emb = (const float*)d_in[0];
    const float* Wq  = (const float*)d_in[1];
    const float* Wk  = (const float*)d_in[2];
    const float* Wv  = (const float*)d_in[3];
    float* out = (float*)d_out;

    unsigned short* Qs = (unsigned short*)d_ws;              // 2 MB each, 6 MB total
    unsigned short* Ks = Qs + (size_t)B_ * T_ * A_;
    unsigned short* Vs = Ks + (size_t)B_ * T_ * A_;

    qkv_proj_kernel<<<dim3(512), dim3(256), 0, stream>>>(emb, Wq, Wk, Wv, Qs, Ks, Vs);
    attn_kernel<<<dim3(1024), dim3(256), 0, stream>>>(Qs, Ks, Vs, out);
}

// Round 4
// 74.624 us; speedup vs baseline: 10.2094x; 1.7965x over previous
//
#include <hip/hip_runtime.h>

#define B_ 4
#define T_ 4096
#define E_ 512
#define A_ 64
#define SQSCALE 0.1803368801111204f   // log2(e)/8 : folds softmax scale + exp->exp2

typedef __attribute__((ext_vector_type(8)))  short bf16x8;
typedef __attribute__((ext_vector_type(8)))  unsigned short ushort8;
typedef __attribute__((ext_vector_type(4)))  float f32x4;
typedef __attribute__((ext_vector_type(16))) float f32x16;

__device__ __forceinline__ unsigned short f2bf(float x) {
    union { float f; unsigned int u; } v; v.f = x;
    unsigned int r = v.u + 0x7fffu + ((v.u >> 16) & 1u);
    return (unsigned short)(r >> 16);
}
__device__ __forceinline__ unsigned pk2(float a, float b) {
    return (unsigned)f2bf(a) | ((unsigned)f2bf(b) << 16);
}
// v_permlane32_swap_b32 a,b: a' = [a_lo | b_lo], b' = [a_hi | b_hi]
// (only ever called with two DISTINCT values -> no same-register hazard)
__device__ __forceinline__ void pls(unsigned &a, unsigned &b) {
    asm("v_permlane32_swap_b32 %0, %1" : "+v"(a), "+v"(b));
}
__device__ __forceinline__ bf16x8 cvt8(float4 a, float4 b) {
    union { unsigned short s[8]; bf16x8 v; } u;
    u.s[0] = f2bf(a.x); u.s[1] = f2bf(a.y); u.s[2] = f2bf(a.z); u.s[3] = f2bf(a.w);
    u.s[4] = f2bf(b.x); u.s[5] = f2bf(b.y); u.s[6] = f2bf(b.z); u.s[7] = f2bf(b.w);
    return u.v;
}

// ------------- Kernel 0: W -> Wct bf16 [192][512] (n-major), Q cols pre-scaled
__global__ __launch_bounds__(256) void prep_w(
    const float* __restrict__ Wq, const float* __restrict__ Wk,
    const float* __restrict__ Wv, unsigned short* __restrict__ Wct)
{
    const int id = blockIdx.x * 256 + threadIdx.x;   // 192*128 threads
    const int n = id >> 7;
    const int k4 = (id & 127) << 2;
    const float* W = (n < 64) ? Wq : ((n < 128) ? Wk : Wv);
    const int col = n & 63;
    const float sc = (n < 64) ? SQSCALE : 1.f;
    union { unsigned short s[4]; unsigned long long ll; } u;
    #pragma unroll
    for (int j = 0; j < 4; ++j) u.s[j] = f2bf(W[(k4 + j) * 64 + col] * sc);
    *(unsigned long long*)&Wct[(long)n * 512 + k4] = u.ll;
}

// ------------- Kernel 1: QKV projection via bf16 MFMA ----------------------
__global__ __launch_bounds__(256) void qkv_proj_kernel(
    const float* __restrict__ emb, const unsigned short* __restrict__ Wct,
    unsigned short* __restrict__ Qo, unsigned short* __restrict__ Ko,
    unsigned short* __restrict__ Vto)
{
    __shared__ unsigned short vt[64][72];
    const int tid = threadIdx.x, w = tid >> 6, lane = tid & 63;
    const int c = lane & 15, hi = lane >> 4;
    const long rowbase = (long)blockIdx.x * 64 + w * 16;

    f32x4 acc[12];
    #pragma unroll
    for (int nt = 0; nt < 12; ++nt) acc[nt] = (f32x4){0.f, 0.f, 0.f, 0.f};

    const float* __restrict__ arow = emb + (rowbase + c) * 512 + hi * 8;
    float4 a0 = *(const float4*)(arow + 0);
    float4 a1 = *(const float4*)(arow + 4);
    float4 b0 = *(const float4*)(arow + 32);
    float4 b1 = *(const float4*)(arow + 36);

    #pragma unroll
    for (int k2 = 0; k2 < 8; ++k2) {
        const int ksA = 2 * k2, ksB = 2 * k2 + 1;
        const bf16x8 af = cvt8(a0, a1);
        {
            const int kp = (ksA + 2 < 16) ? ksA + 2 : 14;
            a0 = *(const float4*)(arow + kp * 32);
            a1 = *(const float4*)(arow + kp * 32 + 4);
        }
        #pragma unroll
        for (int nt = 0; nt < 12; ++nt) {
            const bf16x8 bf_ = *(const bf16x8*)&Wct[(nt * 16 + c) * 512 + ksA * 32 + hi * 8];
            acc[nt] = __builtin_amdgcn_mfma_f32_16x16x32_bf16(af, bf_, acc[nt], 0, 0, 0);
        }
        const bf16x8 af2 = cvt8(b0, b1);
        {
            const int kp = (ksB + 2 < 16) ? ksB + 2 : 15;
            b0 = *(const float4*)(arow + kp * 32);
            b1 = *(const float4*)(arow + kp * 32 + 4);
        }
        #pragma unroll
        for (int nt = 0; nt < 12; ++nt) {
            const bf16x8 bf_ = *(const bf16x8*)&Wct[(nt * 16 + c) * 512 + ksB * 32 + hi * 8];
            acc[nt] = __builtin_amdgcn_mfma_f32_16x16x32_bf16(af2, bf_, acc[nt], 0, 0, 0);
        }
    }

    #pragma unroll
    for (int nt = 0; nt < 4; ++nt)
        #pragma unroll
        for (int r = 0; r < 4; ++r) {
            Qo[(rowbase + hi * 4 + r) * 64 + nt * 16 + c] = f2bf(acc[nt][r]);
            Ko[(rowbase + hi * 4 + r) * 64 + nt * 16 + c] = f2bf(acc[nt + 4][r]);
            vt[nt * 16 + c][w * 16 + hi * 4 + r] = f2bf(acc[nt + 8][r]);
        }
    __syncthreads();
    const int d = tid >> 2, seg = tid & 3;
    const long vbase = ((long)(blockIdx.x >> 6) * 64 + d) * T_ + (blockIdx.x & 63) * 64 + seg * 16;
    *(ushort8*)&Vto[vbase]     = *(const ushort8*)&vt[d][seg * 16];
    *(ushort8*)&Vto[vbase + 8] = *(const ushort8*)&vt[d][seg * 16 + 8];
}

// ------------- Kernel 2: causal flash attention, swapped-operand 32x32 MFMA -
__global__ __launch_bounds__(256, 2) void attn_kernel(
    const unsigned short* __restrict__ Q, const unsigned short* __restrict__ K,
    const unsigned short* __restrict__ Vt, float* __restrict__ out)
{
    __shared__ float accbuf[4][32][64];   // 32 KB split-K merge
    __shared__ float mbuf[4][32], lbuf[4][32];
    __shared__ float scb[4][32];          // per-wave rescale broadcast

    const int tid = threadIdx.x, w = tid >> 6, lane = tid & 63;
    const int c = lane & 31, h = lane >> 5;
    const int b = blockIdx.x & 3;
    const int u = blockIdx.x >> 2;
    const int t = (u < 64) ? (127 - u) : (u - 64);
    const int qb = t << 5;

    const unsigned short* __restrict__ Qb = Q + ((long)b * T_ + qb) * 64;
    const unsigned short* __restrict__ Kb = K + (long)b * T_ * 64;
    const unsigned short* __restrict__ Vb = Vt + (long)b * 64 * T_;

    // Q^T B-frags: B[k=dim][col=q=c]
    bf16x8 qf[4];
    #pragma unroll
    for (int kk = 0; kk < 4; ++kk)
        qf[kk] = *(const bf16x8*)&Qb[(long)c * 64 + kk * 16 + h * 8];

    f32x16 acc[2];
    #pragma unroll
    for (int ct = 0; ct < 2; ++ct)
        #pragma unroll
        for (int j = 0; j < 16; ++j) acc[ct][j] = 0.f;
    float m = -1e30f, l = 0.f;

    const int nc = ((qb + 31) >> 6) + 1;

    bf16x8 kf[2][4];
    {
        const long s0p = (long)((w < nc) ? w : (nc - 1)) << 6;
        #pragma unroll
        for (int f = 0; f < 2; ++f)
            #pragma unroll
            for (int kk = 0; kk < 4; ++kk)
                kf[f][kk] = *(const bf16x8*)&Kb[(s0p + f * 32 + c) * 64 + kk * 16 + h * 8];
    }

    for (int ci = w; ci < nc; ci += 4) {
        const long s0 = (long)ci << 6;

        bf16x8 vf[4][2];
        #pragma unroll
        for (int ks = 0; ks < 4; ++ks)
            #pragma unroll
            for (int ct = 0; ct < 2; ++ct)
                vf[ks][ct] = *(const bf16x8*)&Vb[(long)(ct * 32 + c) * T_ + s0 + ks * 16 + h * 8];

        // S^T = K Q^T : D[row=key][col=q]
        f32x16 sf[2];
        #pragma unroll
        for (int f = 0; f < 2; ++f) {
            #pragma unroll
            for (int j = 0; j < 16; ++j) sf[f][j] = 0.f;
            #pragma unroll
            for (int kk = 0; kk < 4; ++kk)
                sf[f] = __builtin_amdgcn_mfma_f32_32x32x16_bf16(kf[f][kk], qf[kk], sf[f], 0, 0, 0);
        }

        // prefetch next chunk's K
        bf16x8 kn[2][4];
        {
            const int cin = ci + 4;
            const long s0n = (long)((cin < nc) ? cin : (nc - 1)) << 6;
            #pragma unroll
            for (int f = 0; f < 2; ++f)
                #pragma unroll
                for (int kk = 0; kk < 4; ++kk)
                    kn[f][kk] = *(const bf16x8*)&Kb[(s0n + f * 32 + c) * 64 + kk * 16 + h * 8];
        }

        // causal mask: key = s0 + 32f + (r&3) + 8*(r>>2) + 4h ; q = qb + c
        if ((int)s0 + 63 > qb) {
            #pragma unroll
            for (int f = 0; f < 2; ++f)
                #pragma unroll
                for (int r = 0; r < 16; ++r) {
                    const int key = (int)s0 + f * 32 + ((r & 3) + 8 * (r >> 2)) + 4 * h;
                    if (key > qb + c) sf[f][r] = -1e30f;
                }
        }

        // ---- online softmax (exp2 domain); cross-half via shfl_xor(32) ----
        float pm = sf[0][0];
        #pragma unroll
        for (int f = 0; f < 2; ++f)
            #pragma unroll
            for (int r = 0; r < 16; ++r) pm = fmaxf(pm, sf[f][r]);
        pm = fmaxf(pm, __shfl_xor(pm, 32));

        const float mn = fmaxf(m, pm);
        const float sc = exp2f(m - mn);
        m = mn;
        l *= sc;
        if (h == 0) scb[w][c] = sc;
        asm volatile("s_waitcnt lgkmcnt(0)" ::: "memory");
        __builtin_amdgcn_sched_barrier(0);
        {
            float scr[16];
            #pragma unroll
            for (int r = 0; r < 16; ++r)
                scr[r] = scb[w][((r & 3) + 8 * (r >> 2)) + 4 * h];
            #pragma unroll
            for (int ct = 0; ct < 2; ++ct)
                #pragma unroll
                for (int r = 0; r < 16; ++r) acc[ct][r] *= scr[r];
        }

        float rs = 0.f;
        #pragma unroll
        for (int f = 0; f < 2; ++f)
            #pragma unroll
            for (int r = 0; r < 16; ++r) {
                const float p = exp2f(sf[f][r] - mn);
                sf[f][r] = p;
                rs += p;
            }
        rs += __shfl_xor(rs, 32);
        l += rs;

        // ---- P -> bf16 A-frags via pack + permlane32_swap; then PV ----
        #pragma unroll
        for (int f = 0; f < 2; ++f) {
            unsigned w01 = pk2(sf[f][0], sf[f][1]);
            unsigned w23 = pk2(sf[f][2], sf[f][3]);
            unsigned w45 = pk2(sf[f][4], sf[f][5]);
            unsigned w67 = pk2(sf[f][6], sf[f][7]);
            pls(w01, w45); pls(w23, w67);
            union { unsigned uu[4]; bf16x8 v; } pa0, pa1;
            pa0.uu[0] = w01; pa0.uu[1] = w23; pa0.uu[2] = w45; pa0.uu[3] = w67;
            unsigned x01 = pk2(sf[f][8],  sf[f][9]);
            unsigned x23 = pk2(sf[f][10], sf[f][11]);
            unsigned x45 = pk2(sf[f][12], sf[f][13]);
            unsigned x67 = pk2(sf[f][14], sf[f][15]);
            pls(x01, x45); pls(x23, x67);
            pa1.uu[0] = x01; pa1.uu[1] = x23; pa1.uu[2] = x45; pa1.uu[3] = x67;
            #pragma unroll
            for (int ct = 0; ct < 2; ++ct) {
                acc[ct] = __builtin_amdgcn_mfma_f32_32x32x16_bf16(pa0.v, vf[2 * f][ct],     acc[ct], 0, 0, 0);
                acc[ct] = __builtin_amdgcn_mfma_f32_32x32x16_bf16(pa1.v, vf[2 * f + 1][ct], acc[ct], 0, 0, 0);
            }
        }

        #pragma unroll
        for (int f = 0; f < 2; ++f)
            #pragma unroll
            for (int kk = 0; kk < 4; ++kk) kf[f][kk] = kn[f][kk];
    }

    // ---- split-K merge across the 4 waves ----
    if (h == 0) { mbuf[w][c] = m; lbuf[w][c] = l; }
    #pragma unroll
    for (int ct = 0; ct < 2; ++ct)
        #pragma unroll
        for (int r = 0; r < 16; ++r)
            accbuf[w][((r & 3) + 8 * (r >> 2)) + 4 * h][ct * 32 + c] = acc[ct][r];
    __syncthreads();
    #pragma unroll
    for (int i = 0; i < 8; ++i) {
        const int e = tid + i * 256;
        const int q = e >> 6, d = e & 63;
        const float ms = fmaxf(fmaxf(mbuf[0][q], mbuf[1][q]), fmaxf(mbuf[2][q], mbuf[3][q]));
        float ls = 0.f, os = 0.f;
        #pragma unroll
        for (int wv = 0; wv < 4; ++wv) {
            const float e_ = exp2f(mbuf[wv][q] - ms);
            ls += lbuf[wv][q] * e_;
            os += accbuf[wv][q][d] * e_;
        }
        out[((long)b * T_ + qb + q) * 64 + d] = os / ls;
    }
}

extern "C" void kernel_launch(void* const* d_in, const int* in_sizes, int n_in,
                              void* d_out, int out_size, void* d_ws, size_t ws_size,
                              hipStream_t stream)
{
    const float* emb = (const float*)d_in[0];
    const float* Wq  = (const float*)d_in[1];
    const float* Wk  = (const float*)d_in[2];
    const float* Wv  = (const float*)d_in[3];
    float* out = (float*)d_out;

    unsigned short* Qs  = (unsigned short*)d_ws;
    unsigned short* Ks  = Qs + (size_t)B_ * T_ * A_;
    unsigned short* Vs  = Ks + (size_t)B_ * T_ * A_;
    unsigned short* Wct = Vs + (size_t)B_ * T_ * A_;

    prep_w<<<dim3(96), dim3(256), 0, stream>>>(Wq, Wk, Wv, Wct);
    qkv_proj_kernel<<<dim3(256), dim3(256), 0, stream>>>(emb, Wct, Qs, Ks, Vs);
    attn_kernel<<<dim3(512), dim3(256), 0, stream>>>(Qs, Ks, Vs, out);
}